// Round 1
// baseline (2157.273 us; speedup 1.0000x reference)
//
#include <hip/hip_runtime.h>
#include <hip/hip_bf16.h>
#include <math.h>

#define B_ 4
#define H_ 16
#define S_ 1024
#define R_ 512
#define BQ 64
#define BK 32
#define NTHREADS 512

typedef unsigned short u16;
typedef unsigned int   u32;
typedef short bf16x8 __attribute__((ext_vector_type(8)));
typedef float f32x4  __attribute__((ext_vector_type(4)));

__device__ inline u16 f2bf(float x) {
    union { float f; u32 u; } v; v.f = x;
    u32 r = (v.u + 0x7fffu + ((v.u >> 16) & 1u)) >> 16;
    return (u16)r;
}
__device__ inline u32 pack2(float a, float b) {
    return (u32)f2bf(a) | ((u32)f2bf(b) << 16);
}

#define MFMA16(a, b, c) __builtin_amdgcn_mfma_f32_16x16x32_bf16(a, b, c, 0, 0, 0)

__global__ __launch_bounds__(NTHREADS, 2)
void mla_attn_kernel(const float* __restrict__ qn,
                     const float* __restrict__ ckv,
                     const float* __restrict__ rope,
                     const int*   __restrict__ mask,
                     const int*   __restrict__ cmaskp,
                     float*       __restrict__ out)
{
    const int tid  = threadIdx.x;
    const int lane = tid & 63;
    const int wv   = tid >> 6;     // wave 0..7
    const int l15  = lane & 15;
    const int lq   = lane >> 4;    // quad 0..3

    const int qt = blockIdx.x;
    const int h  = blockIdx.y;
    const int b  = blockIdx.z;
    const int q0 = qt * BQ;

    const int cflag = cmaskp[0];   // low word is 1/0 for int32 or int64

    // LDS: 66560 + 33280 + 40960 + 8448 + 5120 + 768 = 155,136 B (< 160 KiB)
    __shared__ __align__(16) u16   sQ[BQ][520];     // Q tile bf16, pad 520 (row stride 1040B = 65*16)
    __shared__ __align__(16) u16   sCKV[BK][520];   // CKV tile bf16 row-major [kt][r]
    __shared__ __align__(16) u16   sCKVT[R_][40];   // CKV transposed [r][kt], pad 40 (80B rows)
    __shared__ __align__(16) float sS[BQ][33];      // nope scores fp32
    __shared__ __align__(16) u16   sP[BQ][40];      // softmax probs bf16
    __shared__ float sM[BQ];
    __shared__ float sL[BQ];
    __shared__ float sAl[BQ];

    if (tid < BQ) { sM[tid] = -INFINITY; sL[tid] = 0.0f; }

    // ---- stage Q tile: 64x512 fp32 -> bf16 LDS (coalesced, b128 LDS writes) ----
    const float* qbase = qn + ((size_t)((b * H_ + h) * S_ + q0)) * R_;
    #pragma unroll
    for (int i = 0; i < 8; ++i) {
        int flat = tid * 8 + i * 4096;
        int qq = flat >> 9, rr = flat & 511;
        const float4* p = (const float4*)(qbase + (size_t)qq * R_ + rr);
        float4 f0 = p[0], f1 = p[1];
        u32* dst = (u32*)&sQ[qq][rr];
        dst[0] = pack2(f0.x, f0.y);
        dst[1] = pack2(f0.z, f0.w);
        dst[2] = pack2(f1.x, f1.y);
        dst[3] = pack2(f1.z, f1.w);
    }

    // O accumulator: wave owns r-columns [wv*64, wv*64+64), 4x4 tiles of 16x16
    f32x4 acc[4][4];
    #pragma unroll
    for (int i = 0; i < 4; ++i)
        #pragma unroll
        for (int j = 0; j < 4; ++j)
            acc[i][j] = (f32x4){0.f, 0.f, 0.f, 0.f};

    const float* ckvb  = ckv  + (size_t)b * S_ * R_;
    const float* ropeb = rope + ((size_t)(b * H_ + h)) * S_ * S_;
    const int*   maskb = mask + b * S_;
    const int sq = tid >> 3, sj = tid & 7;   // softmax mapping: 8 threads per q-row

    const int nkt = cflag ? ((q0 + BQ) / BK) : (S_ / BK);
    const float SCALE = 0.07216878364870323f;   // 1/sqrt(64+128)

    for (int kt = 0; kt < nkt; ++kt) {
        const int k0 = kt * BK;

        // ---- stage A: prefetch rope+mask into regs; zero sS; CKV -> sCKV ----
        float4 rp = *(const float4*)(ropeb + (size_t)(q0 + sq) * S_ + k0 + sj * 4);
        int4   mk = *(const int4*)(maskb + k0 + sj * 4);

        for (int idx = tid; idx < BQ * 33; idx += NTHREADS)
            ((float*)sS)[idx] = 0.0f;

        #pragma unroll
        for (int i = 0; i < 4; ++i) {
            int flat = tid * 8 + i * 4096;
            int kr = flat >> 9, rr = flat & 511;
            const float4* p = (const float4*)(ckvb + (size_t)(k0 + kr) * R_ + rr);
            float4 f0 = p[0], f1 = p[1];
            u32* dst = (u32*)&sCKV[kr][rr];
            dst[0] = pack2(f0.x, f0.y);
            dst[1] = pack2(f0.z, f0.w);
            dst[2] = pack2(f1.x, f1.y);
            dst[3] = pack2(f1.z, f1.w);
        }
        __syncthreads();   // (1a) sCKV ready, sS zeroed

        // ---- stage B: transpose sCKV -> sCKVT (column reads are conflict-free) ----
        {
            u16 vals[BK];
            #pragma unroll
            for (int kk = 0; kk < BK; ++kk) vals[kk] = sCKV[kk][tid];
            #pragma unroll
            for (int c = 0; c < 4; ++c) {
                u32* dst = (u32*)&sCKVT[tid][c * 8];
                dst[0] = (u32)vals[c*8+0] | ((u32)vals[c*8+1] << 16);
                dst[1] = (u32)vals[c*8+2] | ((u32)vals[c*8+3] << 16);
                dst[2] = (u32)vals[c*8+4] | ((u32)vals[c*8+5] << 16);
                dst[3] = (u32)vals[c*8+6] | ((u32)vals[c*8+7] << 16);
            }
        }
        __syncthreads();   // (1b)

        // ---- matmul-1: nope = Q . CKV^T, r-split over waves, ds_add reduce ----
        {
            const int mt = wv & 1;     // q-half (32 rows)
            const int rh = wv >> 1;    // r-chunk of 128
            const int qb = mt * 32;
            f32x4 s00 = {0,0,0,0}, s01 = {0,0,0,0}, s10 = {0,0,0,0}, s11 = {0,0,0,0};
            #pragma unroll
            for (int st = 0; st < 4; ++st) {
                int r0 = rh * 128 + st * 32 + lq * 8;
                bf16x8 a0 = *(const bf16x8*)&sQ[qb + l15][r0];
                bf16x8 a1 = *(const bf16x8*)&sQ[qb + 16 + l15][r0];
                bf16x8 b0 = *(const bf16x8*)&sCKV[l15][r0];
                bf16x8 b1 = *(const bf16x8*)&sCKV[16 + l15][r0];
                s00 = MFMA16(a0, b0, s00);
                s01 = MFMA16(a0, b1, s01);
                s10 = MFMA16(a1, b0, s10);
                s11 = MFMA16(a1, b1, s11);
            }
            int row = qb + lq * 4;
            #pragma unroll
            for (int reg = 0; reg < 4; ++reg) {
                atomicAdd(&sS[row + reg][l15],           s00[reg]);
                atomicAdd(&sS[row + reg][l15 + 16],      s01[reg]);
                atomicAdd(&sS[row + 16 + reg][l15],      s10[reg]);
                atomicAdd(&sS[row + 16 + reg][l15 + 16], s11[reg]);
            }
        }
        __syncthreads();   // (2) sS complete

        // ---- online softmax (fp32 scores; wave-synchronous per q-row) ----
        {
            float sc0 = (sS[sq][sj*4+0] + rp.x) * SCALE;
            float sc1 = (sS[sq][sj*4+1] + rp.y) * SCALE;
            float sc2 = (sS[sq][sj*4+2] + rp.z) * SCALE;
            float sc3 = (sS[sq][sj*4+3] + rp.w) * SCALE;
            if (mk.x) sc0 = -INFINITY;
            if (mk.y) sc1 = -INFINITY;
            if (mk.z) sc2 = -INFINITY;
            if (mk.w) sc3 = -INFINITY;
            if (cflag) {
                int kbase = k0 + sj * 4, qg = q0 + sq;
                if (kbase + 0 > qg) sc0 = -INFINITY;
                if (kbase + 1 > qg) sc1 = -INFINITY;
                if (kbase + 2 > qg) sc2 = -INFINITY;
                if (kbase + 3 > qg) sc3 = -INFINITY;
            }
            float vm = fmaxf(fmaxf(sc0, sc1), fmaxf(sc2, sc3));
            vm = fmaxf(vm, __shfl_xor(vm, 1));
            vm = fmaxf(vm, __shfl_xor(vm, 2));
            vm = fmaxf(vm, __shfl_xor(vm, 4));
            float mo = sM[sq];             // read before any write (same wave, lockstep)
            float mn = fmaxf(mo, vm);
            float al, p0, p1, p2, p3, rs;
            if (mn == -INFINITY) {         // row fully masked so far: avoid inf-inf NaN
                al = 1.0f; p0 = p1 = p2 = p3 = 0.0f; rs = 0.0f;
            } else {
                al = expf(mo - mn);        // mo=-inf -> 0, correct
                p0 = expf(sc0 - mn);
                p1 = expf(sc1 - mn);
                p2 = expf(sc2 - mn);
                p3 = expf(sc3 - mn);
                rs = (p0 + p1) + (p2 + p3);
            }
            rs += __shfl_xor(rs, 1);
            rs += __shfl_xor(rs, 2);
            rs += __shfl_xor(rs, 4);
            u32* pdst = (u32*)&sP[sq][sj * 4];
            pdst[0] = pack2(p0, p1);
            pdst[1] = pack2(p2, p3);
            if (sj == 0) {
                sM[sq]  = mn;
                sL[sq]  = sL[sq] * al + rs;
                sAl[sq] = al;
            }
        }
        __syncthreads();   // (3) sP, sAl ready

        // ---- matmul-2: O = O*alpha + P . CKV ----
        {
            float alr[4][4];
            #pragma unroll
            for (int mi = 0; mi < 4; ++mi)
                #pragma unroll
                for (int reg = 0; reg < 4; ++reg)
                    alr[mi][reg] = sAl[mi * 16 + lq * 4 + reg];
            #pragma unroll
            for (int mi = 0; mi < 4; ++mi)
                #pragma unroll
                for (int ni = 0; ni < 4; ++ni)
                    #pragma unroll
                    for (int reg = 0; reg < 4; ++reg)
                        acc[mi][ni][reg] *= alr[mi][reg];

            const int kq = lq * 8;
            bf16x8 af[4], bfr[4];
            #pragma unroll
            for (int mi = 0; mi < 4; ++mi)
                af[mi] = *(const bf16x8*)&sP[mi * 16 + l15][kq];
            #pragma unroll
            for (int ni = 0; ni < 4; ++ni)
                bfr[ni] = *(const bf16x8*)&sCKVT[wv * 64 + ni * 16 + l15][kq];
            #pragma unroll
            for (int mi = 0; mi < 4; ++mi)
                #pragma unroll
                for (int ni = 0; ni < 4; ++ni)
                    acc[mi][ni] = MFMA16(af[mi], bfr[ni], acc[mi][ni]);
        }
        __syncthreads();   // (4) protect sCKV/sCKVT/sP for next tile's staging
    }

    // ---- epilogue: O / l ----
    float linv[4][4];
    #pragma unroll
    for (int mi = 0; mi < 4; ++mi)
        #pragma unroll
        for (int reg = 0; reg < 4; ++reg)
            linv[mi][reg] = 1.0f / sL[mi * 16 + lq * 4 + reg];

    float* ob = out + ((size_t)((b * H_ + h) * S_ + q0)) * R_;
    #pragma unroll
    for (int mi = 0; mi < 4; ++mi)
        #pragma unroll
        for (int ni = 0; ni < 4; ++ni)
            #pragma unroll
            for (int reg = 0; reg < 4; ++reg)
                ob[(size_t)(mi * 16 + lq * 4 + reg) * R_ + wv * 64 + ni * 16 + l15]
                    = acc[mi][ni][reg] * linv[mi][reg];
}

extern "C" void kernel_launch(void* const* d_in, const int* in_sizes, int n_in,
                              void* d_out, int out_size, void* d_ws, size_t ws_size,
                              hipStream_t stream)
{
    (void)in_sizes; (void)n_in; (void)out_size; (void)d_ws; (void)ws_size;
    const float* qn   = (const float*)d_in[0];
    const float* ckv  = (const float*)d_in[1];
    const float* rope = (const float*)d_in[2];
    const int*   mask = (const int*)d_in[3];
    const int*   cm   = (const int*)d_in[4];
    float* out = (float*)d_out;

    dim3 grid(S_ / BQ, H_, B_);
    dim3 block(NTHREADS);
    hipLaunchKernelGGL(mla_attn_kernel, grid, block, 0, stream,
                       qn, ckv, rope, mask, cm, out);
}

// Round 2
// 1172.055 us; speedup vs baseline: 1.8406x; 1.8406x over previous
//
#include <hip/hip_runtime.h>
#include <hip/hip_bf16.h>
#include <math.h>

#define B_ 4
#define H_ 16
#define S_ 1024
#define R_ 512
#define BQ 64
#define BK 32
#define NTHREADS 512
#define NKS 16   // K steps in mm1: 512 / 32

typedef unsigned short u16;
typedef unsigned int   u32;
typedef short bf16x8 __attribute__((ext_vector_type(8)));
typedef float f32x4  __attribute__((ext_vector_type(4)));

__device__ inline u16 f2bf(float x) {
    union { float f; u32 u; } v; v.f = x;
    return (u16)((v.u + 0x7fffu + ((v.u >> 16) & 1u)) >> 16);
}
__device__ inline u32 pack2(float a, float b) {
    return (u32)f2bf(a) | ((u32)f2bf(b) << 16);
}

#define MFMA16(a, b, c) __builtin_amdgcn_mfma_f32_16x16x32_bf16(a, b, c, 0, 0, 0)

__global__ __launch_bounds__(NTHREADS, 2)
void mla_attn_kernel(const float* __restrict__ qn,
                     const float* __restrict__ ckv,
                     const float* __restrict__ rope,
                     const int*   __restrict__ mask,
                     const int*   __restrict__ cmaskp,
                     float*       __restrict__ out)
{
    const int tid  = threadIdx.x;
    const int lane = tid & 63;
    const int wv   = tid >> 6;     // wave 0..7
    const int l15  = lane & 15;
    const int lq   = lane >> 4;    // quad 0..3
    const int qg   = wv >> 1;      // q-group 0..3 (16 rows each)
    const int ktg  = wv & 1;       // kt-half 0..1 (16 cols each)

    const int qt = blockIdx.x;
    const int h  = blockIdx.y;
    const int b  = blockIdx.z;
    const int q0 = qt * BQ;

    const int cflag = cmaskp[0];

    // LDS: 33280 + 40960 + 5120 = 79,360 B  -> 2 blocks/CU (158,720 <= 160 KiB)
    __shared__ __align__(16) u16 sCKV[BK][520];   // CKV tile bf16 [kt][r], 1040 B rows
    __shared__ __align__(16) u16 sCKVT[R_][40];   // CKV transposed [r][kt], 80 B rows
    // sP row layout (40 u16 = 80 B): cols 0..31 = P bf16; pad bytes per row:
    //   f32 @ col 32 = alpha; f32 @ col 34 = exchange slot ktg0; f32 @ col 36 = slot ktg1
    __shared__ __align__(16) u16 sP[BQ][40];

    // ---- Q fragments in registers: wave qg owns q rows [qg*16, qg*16+16), full K=512 ----
    // A-frag layout (16x16x32): lane m = l15, k = lq*8 + j  -> row q0+qg*16+l15, r = 32s+lq*8
    bf16x8 aq[NKS];
    {
        const float* qrow = qn + ((size_t)((b * H_ + h) * S_ + q0 + qg * 16 + l15)) * R_;
        #pragma unroll
        for (int s = 0; s < NKS; ++s) {
            const float* p = qrow + 32 * s + lq * 8;
            float4 f0 = *(const float4*)p;
            float4 f1 = *(const float4*)(p + 4);
            u32 w0 = pack2(f0.x, f0.y), w1 = pack2(f0.z, f0.w);
            u32 w2 = pack2(f1.x, f1.y), w3 = pack2(f1.z, f1.w);
            union { u32 u[4]; bf16x8 v; } cv;
            cv.u[0] = w0; cv.u[1] = w1; cv.u[2] = w2; cv.u[3] = w3;
            aq[s] = cv.v;
        }
    }

    // O accumulator: wave owns r-columns [wv*64, wv*64+64), 4x4 tiles of 16x16
    f32x4 acc[4][4];
    #pragma unroll
    for (int i = 0; i < 4; ++i)
        #pragma unroll
        for (int j = 0; j < 4; ++j)
            acc[i][j] = (f32x4){0.f, 0.f, 0.f, 0.f};

    // per-row softmax state (rows qg*16 + 4*lq + reg), replicated across l15 lanes
    float m_run[4], l_run[4];
    #pragma unroll
    for (int r = 0; r < 4; ++r) { m_run[r] = -INFINITY; l_run[r] = 0.0f; }

    const float* ckvb  = ckv  + (size_t)b * S_ * R_;
    const float* ropeb = rope + ((size_t)(b * H_ + h)) * S_ * S_;
    const int*   maskb = mask + b * S_;

    const int nkt = cflag ? ((q0 + BQ) / BK) : (S_ / BK);
    const float SCALE = 0.07216878364870323f;   // 1/sqrt(64+128)

    const int rowg0 = q0 + qg * 16 + 4 * lq;    // + reg gives global q row

    float rp[4];   // rope values for (row=4lq+reg, col=ktg*16+l15) of current tile
    int   mkv;     // mask value for col

    // ---- prologue: stage tile 0 + prefetch rope/mask for tile 0 ----
    {
        #pragma unroll
        for (int reg = 0; reg < 4; ++reg)
            rp[reg] = ropeb[(size_t)(rowg0 + reg) * S_ + ktg * 16 + l15];
        mkv = maskb[ktg * 16 + l15];

        #pragma unroll
        for (int i = 0; i < 4; ++i) {
            int flat = tid * 8 + i * 4096;
            int kr = flat >> 9, rr = flat & 511;
            const float4* p = (const float4*)(ckvb + (size_t)kr * R_ + rr);
            float4 f0 = p[0], f1 = p[1];
            u32* dst = (u32*)&sCKV[kr][rr];
            dst[0] = pack2(f0.x, f0.y);
            dst[1] = pack2(f0.z, f0.w);
            dst[2] = pack2(f1.x, f1.y);
            dst[3] = pack2(f1.z, f1.w);
        }
    }
    __syncthreads();   // barrier A: sCKV(0) ready

    for (int kt = 0; kt < nkt; ++kt) {
        const int k0 = kt * BK;

        // ---- phase 1: transpose sCKV -> sCKVT, mm1 (full-K 16x16 tile per wave),
        //      in-wave row max, write exchange slot ----
        {
            u16 vals[BK];
            #pragma unroll
            for (int kk = 0; kk < BK; ++kk) vals[kk] = sCKV[kk][tid];
            #pragma unroll
            for (int c = 0; c < 4; ++c) {
                u32* dst = (u32*)&sCKVT[tid][c * 8];
                dst[0] = (u32)vals[c*8+0] | ((u32)vals[c*8+1] << 16);
                dst[1] = (u32)vals[c*8+2] | ((u32)vals[c*8+3] << 16);
                dst[2] = (u32)vals[c*8+4] | ((u32)vals[c*8+5] << 16);
                dst[3] = (u32)vals[c*8+6] | ((u32)vals[c*8+7] << 16);
            }
        }

        f32x4 sc0 = {0.f,0.f,0.f,0.f}, sc1 = {0.f,0.f,0.f,0.f};
        #pragma unroll
        for (int s = 0; s < NKS; s += 2) {
            bf16x8 bf0 = *(const bf16x8*)&sCKV[ktg * 16 + l15][32 * s + lq * 8];
            bf16x8 bf1 = *(const bf16x8*)&sCKV[ktg * 16 + l15][32 * (s + 1) + lq * 8];
            sc0 = MFMA16(aq[s],     bf0, sc0);
            sc1 = MFMA16(aq[s + 1], bf1, sc1);
        }

        float scf[4], vm[4];
        {
            const int colg = k0 + ktg * 16 + l15;
            #pragma unroll
            for (int reg = 0; reg < 4; ++reg) {
                float v = (sc0[reg] + sc1[reg] + rp[reg]) * SCALE;
                if (mkv) v = -INFINITY;
                if (cflag && colg > rowg0 + reg) v = -INFINITY;
                scf[reg] = v;
                vm[reg]  = v;
            }
            #pragma unroll
            for (int m = 1; m <= 8; m <<= 1)
                #pragma unroll
                for (int reg = 0; reg < 4; ++reg)
                    vm[reg] = fmaxf(vm[reg], __shfl_xor(vm[reg], m));
            if (l15 == 0) {
                #pragma unroll
                for (int reg = 0; reg < 4; ++reg)
                    *(float*)&sP[qg * 16 + 4 * lq + reg][34 + 2 * ktg] = vm[reg];
            }
        }
        __syncthreads();   // barrier B: sCKVT + exchange slots ready

        // ---- phase 2: finish softmax (combine kt-halves), write P + alpha ----
        {
            float pv[4], alpha[4], rs[4];
            #pragma unroll
            for (int reg = 0; reg < 4; ++reg) {
                float pm = *(const float*)&sP[qg * 16 + 4 * lq + reg][34 + 2 * (ktg ^ 1)];
                float mn = fmaxf(m_run[reg], fmaxf(vm[reg], pm));
                if (mn == -INFINITY) {
                    alpha[reg] = 1.0f; pv[reg] = 0.0f;
                } else {
                    alpha[reg] = __expf(m_run[reg] - mn);   // m_run=-inf -> 0
                    pv[reg]    = __expf(scf[reg] - mn);     // scf=-inf -> 0
                }
                m_run[reg] = mn;
                rs[reg] = pv[reg];
            }
            #pragma unroll
            for (int m = 1; m <= 8; m <<= 1)
                #pragma unroll
                for (int reg = 0; reg < 4; ++reg)
                    rs[reg] += __shfl_xor(rs[reg], m);
            #pragma unroll
            for (int reg = 0; reg < 4; ++reg) {
                l_run[reg] = l_run[reg] * alpha[reg] + rs[reg];
                sP[qg * 16 + 4 * lq + reg][ktg * 16 + l15] = f2bf(pv[reg]);
            }
            if (ktg == 0 && l15 == 0) {
                #pragma unroll
                for (int reg = 0; reg < 4; ++reg)
                    *(float*)&sP[qg * 16 + 4 * lq + reg][32] = alpha[reg];
            }
        }
        __syncthreads();   // barrier C: sP (P + alpha) ready

        // ---- phase 3: mm2 (O = O*alpha + P . CKV) + pipelined stage of tile kt+1 ----
        {
            // kick off next tile's global loads first so they overlap the MFMAs
            float4 st_f[4][2];
            const bool more = (kt + 1 < nkt);
            if (more) {
                const int k0n = k0 + BK;
                #pragma unroll
                for (int i = 0; i < 4; ++i) {
                    int flat = tid * 8 + i * 4096;
                    int kr = flat >> 9, rr = flat & 511;
                    const float4* p = (const float4*)(ckvb + (size_t)(k0n + kr) * R_ + rr);
                    st_f[i][0] = p[0];
                    st_f[i][1] = p[1];
                }
                #pragma unroll
                for (int reg = 0; reg < 4; ++reg)
                    rp[reg] = ropeb[(size_t)(rowg0 + reg) * S_ + k0n + ktg * 16 + l15];
                mkv = maskb[k0n + ktg * 16 + l15];
            }

            float alr[4][4];
            #pragma unroll
            for (int mi = 0; mi < 4; ++mi)
                #pragma unroll
                for (int reg = 0; reg < 4; ++reg)
                    alr[mi][reg] = *(const float*)&sP[mi * 16 + 4 * lq + reg][32];
            #pragma unroll
            for (int mi = 0; mi < 4; ++mi)
                #pragma unroll
                for (int ni = 0; ni < 4; ++ni)
                    #pragma unroll
                    for (int reg = 0; reg < 4; ++reg)
                        acc[mi][ni][reg] *= alr[mi][reg];

            const int kq = lq * 8;
            bf16x8 af[4], bfr[4];
            #pragma unroll
            for (int mi = 0; mi < 4; ++mi)
                af[mi] = *(const bf16x8*)&sP[mi * 16 + l15][kq];
            #pragma unroll
            for (int ni = 0; ni < 4; ++ni)
                bfr[ni] = *(const bf16x8*)&sCKVT[wv * 64 + ni * 16 + l15][kq];
            #pragma unroll
            for (int mi = 0; mi < 4; ++mi)
                #pragma unroll
                for (int ni = 0; ni < 4; ++ni)
                    acc[mi][ni] = MFMA16(af[mi], bfr[ni], acc[mi][ni]);

            if (more) {
                #pragma unroll
                for (int i = 0; i < 4; ++i) {
                    int flat = tid * 8 + i * 4096;
                    int kr = flat >> 9, rr = flat & 511;
                    u32* dst = (u32*)&sCKV[kr][rr];
                    dst[0] = pack2(st_f[i][0].x, st_f[i][0].y);
                    dst[1] = pack2(st_f[i][0].z, st_f[i][0].w);
                    dst[2] = pack2(st_f[i][1].x, st_f[i][1].y);
                    dst[3] = pack2(st_f[i][1].z, st_f[i][1].w);
                }
            }
        }
        __syncthreads();   // barrier D (= barrier A of tile kt+1)
    }

    // ---- epilogue: exchange per-row l across kt-half waves, then O / l ----
    if (l15 == 0) {
        #pragma unroll
        for (int reg = 0; reg < 4; ++reg)
            *(float*)&sP[qg * 16 + 4 * lq + reg][34 + 2 * ktg] = l_run[reg];
    }
    __syncthreads();

    float linv[4][4];
    #pragma unroll
    for (int mi = 0; mi < 4; ++mi)
        #pragma unroll
        for (int reg = 0; reg < 4; ++reg) {
            int row = mi * 16 + 4 * lq + reg;
            float lt = *(const float*)&sP[row][34] + *(const float*)&sP[row][36];
            linv[mi][reg] = 1.0f / lt;
        }

    float* ob = out + ((size_t)((b * H_ + h) * S_ + q0)) * R_;
    #pragma unroll
    for (int mi = 0; mi < 4; ++mi)
        #pragma unroll
        for (int ni = 0; ni < 4; ++ni)
            #pragma unroll
            for (int reg = 0; reg < 4; ++reg)
                ob[(size_t)(mi * 16 + 4 * lq + reg) * R_ + wv * 64 + ni * 16 + l15]
                    = acc[mi][ni][reg] * linv[mi][reg];
}

extern "C" void kernel_launch(void* const* d_in, const int* in_sizes, int n_in,
                              void* d_out, int out_size, void* d_ws, size_t ws_size,
                              hipStream_t stream)
{
    (void)in_sizes; (void)n_in; (void)out_size; (void)d_ws; (void)ws_size;
    const float* qn   = (const float*)d_in[0];
    const float* ckv  = (const float*)d_in[1];
    const float* rope = (const float*)d_in[2];
    const int*   mask = (const int*)d_in[3];
    const int*   cm   = (const int*)d_in[4];
    float* out = (float*)d_out;

    dim3 grid(S_ / BQ, H_, B_);
    dim3 block(NTHREADS);
    hipLaunchKernelGGL(mla_attn_kernel, grid, block, 0, stream,
                       qn, ckv, rope, mask, cm, out);
}